// Round 12
// baseline (664.099 us; speedup 1.0000x reference)
//
#include <hip/hip_runtime.h>
#include <math.h>

#define B_ 64
#define L_ 512
#define C_ 256
#define H_ 4
#define LAY 3
#define NEGV -1e9f

#define GF_BIAS  1
#define GF_RELU  2
#define GF_OBF16 4
#define GF_GRU   8

typedef __attribute__((ext_vector_type(8))) short short8;
typedef __attribute__((ext_vector_type(4))) short short4v;
typedef __attribute__((ext_vector_type(4))) float floatx4;

static __device__ __forceinline__ float rcp_(float x) { return __builtin_amdgcn_rcpf(x); }
static __device__ __forceinline__ float sig_(float x) { return rcp_(1.f + __expf(-x)); }
static __device__ __forceinline__ float tanh_(float x) {
    float e = __expf(2.f * x);
    return 1.f - 2.f * rcp_(e + 1.f);
}

static __device__ __forceinline__ short f2bf(float f) {
    unsigned x = __float_as_uint(f);
    x += 0x7fffu + ((x >> 16) & 1u);       // round-to-nearest-even to bf16
    return (short)(x >> 16);
}
static __device__ __forceinline__ float bf2f(short s) {
    return __uint_as_float(((unsigned)(unsigned short)s) << 16);
}

// XCD-aligned token swizzle for elementwise consumers (matches GEMM rb%8 = XCD).
static __device__ __forceinline__ int tok_swizzle(int blk) {
    int c8 = blk & 7, i = blk >> 3;
    return (c8 + 8 * (i >> 5)) * 128 + (i & 31) * 4;
}

static __device__ __forceinline__ void gl_lds16(const short* g, short* l) {
    __builtin_amdgcn_global_load_lds(
        (const __attribute__((address_space(1))) unsigned int*)g,
        (__attribute__((address_space(3))) unsigned int*)l, 16, 0, 0);
}

// ---------------- mask / logical-position scan + pos_of_logical ----------------
__global__ void scan_kernel(const int* __restrict__ x, int* __restrict__ mask,
                            int* __restrict__ logical, int* __restrict__ pol,
                            int* __restrict__ nvalid) {
    int b = blockIdx.x, t = threadIdx.x;
    __shared__ int s[L_];
    int m = (x[b * L_ + t] != 0) ? 1 : 0;
    s[t] = m;
    __syncthreads();
    for (int off = 1; off < L_; off <<= 1) {
        int v = (t >= off) ? s[t - off] : 0;
        __syncthreads();
        s[t] += v;
        __syncthreads();
    }
    int cum = s[t];
    int lg = cum - 1; if (lg < 0) lg = 0;
    mask[b * L_ + t] = m;
    logical[b * L_ + t] = lg;
    if (m) pol[b * L_ + lg] = t;
    if (t == L_ - 1) nvalid[b] = cum;
}

// ---------------- hb = bf16((emb[x] + pos*mf)*mf) ----------------
__global__ void embed_kernel(const int* __restrict__ x, const float* __restrict__ emb,
                             const float* __restrict__ pos, short* __restrict__ hb) {
    int t = threadIdx.x;
    int bl = tok_swizzle(blockIdx.x) + (t >> 6);
    int lane = t & 63;
    int xv = x[bl];
    float mf = (xv != 0) ? 1.f : 0.f;
    int l = bl & (L_ - 1);
    float4 e = *(const float4*)&emb[(size_t)xv * C_ + lane * 4];
    float4 p = *(const float4*)&pos[(size_t)l * C_ + lane * 4];
    short4v hv4;
    hv4.x = f2bf((e.x + p.x * mf) * mf);
    hv4.y = f2bf((e.y + p.y * mf) * mf);
    hv4.z = f2bf((e.z + p.z * mf) * mf);
    hv4.w = f2bf((e.w + p.w * mf) * mf);
    *(short4v*)&hb[(size_t)bl * C_ + lane * 4] = hv4;
}

// ---------------- weight prep ----------------
__global__ void f2bf_kernel(const float* __restrict__ s, short* __restrict__ d, int n) {
    int i = blockIdx.x * 256 + threadIdx.x;
    if (i < n) d[i] = f2bf(s[i]);
}

// W2cat[l][512][256]: rows 0..255 = gpW[l], 256..511 = gfW[l]
__global__ void prep_w2(const float* __restrict__ gpW, const float* __restrict__ gfW,
                        short* __restrict__ W2) {
    int i = blockIdx.x * 256 + threadIdx.x;
    if (i >= 3 * 512 * 256) return;
    int k = i & 255, r = (i >> 8) & 511, l = i >> 17;
    float v = (r < 256) ? gpW[((size_t)l * 256 + r) * 256 + k]
                        : gfW[((size_t)l * 256 + (r - 256)) * 256 + k];
    W2[i] = f2bf(v);
}

// Asd[l][128][512]: n<16 encodes (type,dir,head): n = type*8 + dir*4 + h.
__global__ void prep_asd(const float* __restrict__ gpas, const float* __restrict__ gpad,
                         const float* __restrict__ gfas, const float* __restrict__ gfad,
                         short* __restrict__ Asd) {
    int i = blockIdx.x * 256 + threadIdx.x;
    if (i >= 3 * 128 * 512) return;
    int k = i & 511, n = (i >> 9) & 127, l = i >> 16;
    float v = 0.f;
    if (n < 16) {
        int type = n >> 3;          // 0 = src(s), 1 = dst(d)
        int dir = (n >> 2) & 1;     // 0 = past, 1 = future
        int hh = n & 3;
        int kk = k - dir * 256;
        if (kk >= 0 && kk < 256 && (kk >> 6) == hh) {
            const float* a = type ? (dir ? gfad : gpad) : (dir ? gfas : gpas);
            v = a[l * 256 + kk];
        }
    }
    Asd[i] = f2bf(v);
}

// Interleaved GRU weights: Bc[l][n'][512], n' = 4*ch + g, g in {0:r,1:z,2:i,3:n}.
__global__ void prep_gru_i(const float* __restrict__ Wih, const float* __restrict__ Whh,
                           short* __restrict__ Bc) {
    int i = blockIdx.x * 256 + threadIdx.x;
    if (i >= 3 * 1024 * 512) return;
    int k = i & 511, np = (i >> 9) & 1023, l = i >> 19;
    int ch = np >> 2, g = np & 3;
    float v = 0.f;
    if (g < 2) {
        v = (k < 256) ? Wih[((size_t)l * 768 + g * 256 + ch) * 256 + k]
                      : Whh[((size_t)l * 768 + g * 256 + ch) * 256 + (k - 256)];
    } else if (g == 2) {
        if (k < 256) v = Wih[((size_t)l * 768 + 512 + ch) * 256 + k];
    } else {
        if (k >= 256) v = Whh[((size_t)l * 768 + 512 + ch) * 256 + (k - 256)];
    }
    Bc[i] = f2bf(v);
}

// bias4[l][4*ch+g]
__global__ void prep_bias4(const float* __restrict__ bih, const float* __restrict__ bhh,
                           float* __restrict__ bc) {
    int i = blockIdx.x * 256 + threadIdx.x;
    if (i >= 3 * 1024) return;
    int np = i & 1023, l = i >> 10;
    int ch = np >> 2, g = np & 3;
    float v;
    if (g < 2)       v = bih[l * 768 + g * 256 + ch] + bhh[l * 768 + g * 256 + ch];
    else if (g == 2) v = bih[l * 768 + 512 + ch];
    else             v = bhh[l * 768 + 512 + ch];
    bc[i] = v;
}

// ---------------- bf16 MFMA GEMM: C[M,N] = A[M,K] * B[N,K]^T ----------------
// 1D grid, XCD-sequential: id%8 = XCD = rb%8; (id>>3) cycles col-blocks fastest.
// Operand-swapped MFMA: lane owns 4 consecutive cols of one row (packed stores).
// GF_GRU: interleaved-B epilogue, fast transcendentals, hprev register-prefetch,
// LDS-transposed (stride 36) coalesced bf16 hn2 store.
__global__ __launch_bounds__(256) void bgemm(const short* __restrict__ A0,
                                             const short* __restrict__ A1,
                                             const short* __restrict__ Bw,
                                             void* __restrict__ Cout,
                                             const float* __restrict__ bias,
                                             const short* __restrict__ hprev,
                                             int K, int lda, int ldc, int nstore,
                                             int cbBits, int flags) {
    __shared__ short As[128 * 36];   // K-loop uses stride 32; GRU staging stride 36
    __shared__ short Bs[128 * 32];
    const int id = blockIdx.x;
    const int cb = (id >> 3) & ((1 << cbBits) - 1);
    const int rb = (id & 7) + ((id >> (3 + cbBits)) << 3);
    const int tid = threadIdx.x;
    const int wave = tid >> 6, lane = tid & 63;
    const int wm = wave >> 1, wn = wave & 1;
    const size_t arow0 = (size_t)rb * 128;
    const short* Bb = Bw + (size_t)cb * 128 * K;
    const int srow = lane >> 2;
    const int sq = (lane & 3) * 8;
    const int q = lane >> 4, t16 = lane & 15;

    // GRU: prefetch h_prev early (latency hidden under K-loop)
    float hp[4][4];
    if (flags & GF_GRU) {
#pragma unroll
        for (int nf = 0; nf < 4; nf++) {
            int ch = cb * 32 + wn * 16 + nf * 4 + q;
#pragma unroll
            for (int mf = 0; mf < 4; mf++) {
                int row = rb * 128 + wm * 64 + mf * 16 + t16;
                hp[nf][mf] = bf2f(hprev[(size_t)row * 256 + ch]);
            }
        }
    }

    floatx4 acc[4][4];   // [nf][mf]
#pragma unroll
    for (int i = 0; i < 4; i++)
#pragma unroll
        for (int j = 0; j < 4; j++) acc[i][j] = (floatx4)0.f;

    for (int k0 = 0; k0 < K; k0 += 32) {
        bool useA1 = (A1 != nullptr) && (k0 >= 256);
        const short* Abase = useA1 ? (A1 + arow0 * 256 + (k0 - 256))
                                   : (A0 + arow0 * (size_t)lda + k0);
        int astr = useA1 ? 256 : lda;
#pragma unroll
        for (int t = 0; t < 2; ++t) {
            int r = (wave * 2 + t) * 16 + srow;
            gl_lds16(Abase + (size_t)r * astr + sq, &As[r * 32 + sq]);
            gl_lds16(Bb + (size_t)r * K + k0 + sq, &Bs[r * 32 + sq]);
        }
        __syncthreads();
        short8 af[4], bfr[4];
#pragma unroll
        for (int mf = 0; mf < 4; mf++)
            af[mf] = *(const short8*)&As[(wm * 64 + mf * 16 + t16) * 32 + q * 8];
#pragma unroll
        for (int nf = 0; nf < 4; nf++)
            bfr[nf] = *(const short8*)&Bs[(wn * 64 + nf * 16 + t16) * 32 + q * 8];
#pragma unroll
        for (int mf = 0; mf < 4; mf++)
#pragma unroll
            for (int nf = 0; nf < 4; nf++)
                acc[nf][mf] = __builtin_amdgcn_mfma_f32_16x16x32_bf16(
                    bfr[nf], af[mf], acc[nf][mf], 0, 0, 0);
        __syncthreads();
    }

    const int rowbase = rb * 128 + wm * 64;
    const int colbase = cb * 128 + wn * 64;

    if (flags & GF_GRU) {
        // gates from fp32 accs -> bf16 hn2 tile staged in LDS (stride 36, no conflicts)
#pragma unroll
        for (int nf = 0; nf < 4; nf++) {
            int col0 = colbase + nf * 16 + q * 4;
            float4 bv4 = *(const float4*)&bias[col0];
            int chl = wn * 16 + nf * 4 + q;
#pragma unroll
            for (int mf = 0; mf < 4; mf++) {
                int lrow = wm * 64 + mf * 16 + t16;
                float r = sig_(acc[nf][mf][0] + bv4.x);
                float z = sig_(acc[nf][mf][1] + bv4.y);
                float nv = tanh_((acc[nf][mf][2] + bv4.z) + r * (acc[nf][mf][3] + bv4.w));
                As[lrow * 36 + chl] = f2bf((1.f - z) * nv + z * hp[nf][mf]);
            }
        }
        __syncthreads();
        // coalesced write: 128 rows x 32 ch, short4 chunks
        const int chbase = cb * 32;
#pragma unroll
        for (int it = 0; it < 4; it++) {
            int unit = tid + it * 256;
            int rowl = unit >> 3, ck = unit & 7;
            size_t grow = (size_t)rb * 128 + rowl;
            *(short4v*)&((short*)Cout)[grow * 256 + chbase + ck * 4] =
                *(const short4v*)&As[rowl * 36 + ck * 4];
        }
        return;
    }

#pragma unroll
    for (int nf = 0; nf < 4; nf++) {
        int col0 = colbase + nf * 16 + q * 4;
        if (col0 >= nstore) continue;
        float4 bv4 = make_float4(0.f, 0.f, 0.f, 0.f);
        if (flags & GF_BIAS) bv4 = *(const float4*)&bias[col0];
#pragma unroll
        for (int mf = 0; mf < 4; mf++) {
            int row = rowbase + mf * 16 + t16;
            float v0 = acc[nf][mf][0] + bv4.x;
            float v1 = acc[nf][mf][1] + bv4.y;
            float v2 = acc[nf][mf][2] + bv4.z;
            float v3 = acc[nf][mf][3] + bv4.w;
            if (flags & GF_RELU) {
                v0 = fmaxf(v0, 0.f); v1 = fmaxf(v1, 0.f);
                v2 = fmaxf(v2, 0.f); v3 = fmaxf(v3, 0.f);
            }
            size_t base = (size_t)row * ldc + col0;
            if (flags & GF_OBF16) {
                short4v pk;
                pk.x = f2bf(v0); pk.y = f2bf(v1); pk.z = f2bf(v2); pk.w = f2bf(v3);
                *(short4v*)&((short*)Cout)[base] = pk;
            } else {
                float4 pk = make_float4(v0, v1, v2, v3);
                *(float4*)&((float*)Cout)[base] = pk;
            }
        }
    }
}

// ---------------- LayerNorm over hn2 (bf16) + mask -> hb ----------------
__global__ __launch_bounds__(256) void ln_kernel(
    const short* __restrict__ hn2b, short* __restrict__ hb,
    const int* __restrict__ mask,
    const float* __restrict__ lng, const float* __restrict__ lnb) {
    int t = threadIdx.x;
    int bl = tok_swizzle(blockIdx.x) + (t >> 6);
    int lane = t & 63;
    short4v v4 = *(const short4v*)&hn2b[(size_t)bl * C_ + lane * 4];
    float v[4] = {bf2f(v4.x), bf2f(v4.y), bf2f(v4.z), bf2f(v4.w)};
    float s = (v[0] + v[1]) + (v[2] + v[3]);
    float ss = (v[0] * v[0] + v[1] * v[1]) + (v[2] * v[2] + v[3] * v[3]);
#pragma unroll
    for (int off = 32; off; off >>= 1) {
        s += __shfl_xor(s, off);
        ss += __shfl_xor(ss, off);
    }
    float mu = s * (1.f / 256.f);
    float var = ss * (1.f / 256.f) - mu * mu;
    float rstd = rsqrtf(fmaxf(var, 0.f) + 1e-5f);
    float4 lg = *(const float4*)&lng[lane * 4];
    float4 lb = *(const float4*)&lnb[lane * 4];
    float mfv = mask[bl] ? 1.f : 0.f;
    short4v yb;
    yb.x = f2bf(((v[0] - mu) * rstd * lg.x + lb.x) * mfv);
    yb.y = f2bf(((v[1] - mu) * rstd * lg.y + lb.y) * mfv);
    yb.z = f2bf(((v[2] - mu) * rstd * lg.z + lb.z) * mfv);
    yb.w = f2bf(((v[3] - mu) * rstd * lg.w + lb.w) * mfv);
    *(short4v*)&hb[(size_t)bl * C_ + lane * 4] = yb;
}

// ---------------- sparse GAT aggregation, vectorized short8, both dirs ----------------
__global__ __launch_bounds__(256) void agg_fused(
    const short* __restrict__ hpb2, const float* __restrict__ S,
    const int* __restrict__ mask, const int* __restrict__ logical,
    const int* __restrict__ pol, const int* __restrict__ nvalid,
    short* __restrict__ m, int dil) {
    int t = threadIdx.x;
    int bl = tok_swizzle(blockIdx.x) + (t >> 6);
    int sub = t & 63;
    int dir = sub >> 5;
    int slot = sub & 31;
    int cb = slot * 8;
    int head = slot >> 3;
    int b = bl >> 9;

    int mi = mask[bl];
    int li = logical[bl];
    int nv = nvalid[b];
    int js[3]; int nn = 0;
    if (mi) {
#pragma unroll
        for (int k = 1; k <= 3; k++) {
            int lj = dir ? (li - k * dil) : (li + k * dil);
            if (lj >= 0 && lj < nv) js[nn++] = pol[b * L_ + lj];
        }
    }
    int sn = dir * 4 + head, dn = 8 + sn;
    float si = S[(size_t)bl * 16 + sn];
    float di = S[(size_t)bl * 16 + dn];
    float e0 = si + di; e0 = e0 > 0.f ? e0 : 0.2f * e0;
    float emax = e0, ev[3];
    for (int k = 0; k < nn; k++) {
        float djv = S[((size_t)(b * L_ + js[k])) * 16 + dn];
        float e = si + djv; e = e > 0.f ? e : 0.2f * e;
        ev[k] = e; emax = fmaxf(emax, e);
    }
    float w0 = __expf(e0 - emax), den = w0;
    float wv[3];
    for (int k = 0; k < nn; k++) { wv[k] = __expf(ev[k] - emax); den += wv[k]; }
    float rden = rcp_(den);

    size_t base = (size_t)bl * 512 + dir * 256 + cb;
    short8 vself = *(const short8*)&hpb2[base];
    float o[8];
#pragma unroll
    for (int j = 0; j < 8; j++) o[j] = w0 * bf2f(vself[j]);
    for (int k = 0; k < nn; k++) {
        short8 vn = *(const short8*)&hpb2[((size_t)(b * L_ + js[k])) * 512 + dir * 256 + cb];
#pragma unroll
        for (int j = 0; j < 8; j++) o[j] = fmaf(wv[k], bf2f(vn[j]), o[j]);
    }
    short8 ov;
#pragma unroll
    for (int j = 0; j < 8; j++) ov[j] = f2bf(o[j] * rden);
    *(short8*)&m[base] = ov;
}

// ---------------- masked softmax pooling + both heads (bf16 h) ----------------
__global__ __launch_bounds__(1024) void pool_head_kernel(
    const short* __restrict__ hb, const int* __restrict__ mask,
    const float* __restrict__ pw, const float* __restrict__ pb,
    const float* __restrict__ h0W, const float* __restrict__ h0b,
    const float* __restrict__ h1W, const float* __restrict__ h1b,
    float* __restrict__ out) {
    int b = blockIdx.x;
    int t = threadIdx.x;
    int lane = t & 63, wave = t >> 6;
    __shared__ float sc[L_];
    __shared__ float red[20];
    __shared__ float part[4][C_];
    __shared__ float pooled[C_];

    float4 wv = *(const float4*)&pw[lane * 4];
    for (int l = wave; l < L_; l += 16) {
        short4v hv = *(const short4v*)&hb[((size_t)b * L_ + l) * C_ + lane * 4];
        float p = bf2f(hv.x) * wv.x + bf2f(hv.y) * wv.y
                + bf2f(hv.z) * wv.z + bf2f(hv.w) * wv.w;
#pragma unroll
        for (int off = 32; off; off >>= 1) p += __shfl_down(p, off);
        if (lane == 0) sc[l] = mask[b * L_ + l] ? (p + pb[0]) : NEGV;
    }
    __syncthreads();

    float v = (t < L_) ? sc[t] : NEGV;
    float mx = v;
#pragma unroll
    for (int off = 32; off; off >>= 1) mx = fmaxf(mx, __shfl_down(mx, off));
    if (lane == 0) red[wave] = mx;
    __syncthreads();
    if (t == 0) {
        float g = red[0];
        for (int i = 1; i < 16; i++) g = fmaxf(g, red[i]);
        red[16] = g;
    }
    __syncthreads();
    float gmax = red[16];
    float e = (t < L_) ? __expf(v - gmax) : 0.f;
    float ssum = e;
#pragma unroll
    for (int off = 32; off; off >>= 1) ssum += __shfl_down(ssum, off);
    if (lane == 0) red[wave] = ssum;
    __syncthreads();
    if (t == 0) {
        float g = 0.f;
        for (int i = 0; i < 16; i++) g += red[i];
        red[17] = 1.f / g;
    }
    __syncthreads();
    if (t < L_) sc[t] = e * red[17];
    __syncthreads();

    int g = t >> 8, c = t & 255;
    const short* hrow = &hb[((size_t)b * L_ + g * 128) * C_ + c];
    const float* scg = &sc[g * 128];
    float a0 = 0.f, a1 = 0.f, a2 = 0.f, a3 = 0.f;
    for (int l = 0; l < 128; l += 4) {
        a0 = fmaf(scg[l + 0], bf2f(hrow[(size_t)(l + 0) * C_]), a0);
        a1 = fmaf(scg[l + 1], bf2f(hrow[(size_t)(l + 1) * C_]), a1);
        a2 = fmaf(scg[l + 2], bf2f(hrow[(size_t)(l + 2) * C_]), a2);
        a3 = fmaf(scg[l + 3], bf2f(hrow[(size_t)(l + 3) * C_]), a3);
    }
    part[g][c] = (a0 + a1) + (a2 + a3);
    __syncthreads();
    if (t < C_) pooled[t] = (part[0][t] + part[1][t]) + (part[2][t] + part[3][t]);
    __syncthreads();

    for (int o = wave; o < 70; o += 16) {
        const float* W = (o < 50) ? (h0W + (size_t)o * C_) : (h1W + (size_t)(o - 50) * C_);
        float bb = (o < 50) ? h0b[o] : h1b[o - 50];
        float4 w4 = *(const float4*)&W[lane * 4];
        float4 p4 = *(const float4*)&pooled[lane * 4];
        float s = p4.x * w4.x + p4.y * w4.y + p4.z * w4.z + p4.w * w4.w;
#pragma unroll
        for (int off = 32; off; off >>= 1) s += __shfl_down(s, off);
        if (lane == 0) out[b * 70 + o] = s + bb;
    }
}

extern "C" void kernel_launch(void* const* d_in, const int* in_sizes, int n_in,
                              void* d_out, int out_size, void* d_ws, size_t ws_size,
                              hipStream_t stream) {
    const int*   x    = (const int*)d_in[0];
    const float* emb  = (const float*)d_in[1];
    const float* pos  = (const float*)d_in[2];
    const float* gpW  = (const float*)d_in[3];
    const float* gpas = (const float*)d_in[4];
    const float* gpad = (const float*)d_in[5];
    const float* gfW  = (const float*)d_in[6];
    const float* gfas = (const float*)d_in[7];
    const float* gfad = (const float*)d_in[8];
    const float* msgW = (const float*)d_in[9];
    const float* msgb = (const float*)d_in[10];
    const float* Wih  = (const float*)d_in[11];
    const float* bih  = (const float*)d_in[12];
    const float* Whh  = (const float*)d_in[13];
    const float* bhh  = (const float*)d_in[14];
    const float* lng  = (const float*)d_in[15];
    const float* lnb  = (const float*)d_in[16];
    const float* pw   = (const float*)d_in[17];
    const float* pb   = (const float*)d_in[18];
    const float* h0W  = (const float*)d_in[19];
    const float* h0b  = (const float*)d_in[20];
    const float* h1W  = (const float*)d_in[21];
    const float* h1b  = (const float*)d_in[22];
    float* out = (float*)d_out;

    // Workspace layout, units MW = 1Mi floats = 4 MiB:
    //   hn2b bf16 [32768, 256] =  4 MW   -> [ 0,  4)
    //   hb   bf16 [32768, 256] =  4 MW   -> [ 8, 12)
    //   mmb  bf16 [32768, 256] =  4 MW   -> [12, 16)   (also Ssd fp32 [32768,16])
    //   hpb2 bf16 [32768, 512] =  8 MW   -> [16, 24)
    //   mb   bf16 [32768, 512] =  8 MW   -> [24, 32)
    //   weights/bias/masks               -> [32, ~33.4)
    const size_t MW = 1024 * 1024;
    float* ws = (float*)d_ws;
    short* hn2b = (short*)ws;
    short* hb   = (short*)(ws + 8 * MW);
    short* mmb  = (short*)(ws + 12 * MW);
    float* Ssd  = ws + 12 * MW;                          // aliases mmb (timeshared)
    short* hpb2 = (short*)(ws + 16 * MW);
    short* mb   = (short*)(ws + 24 * MW);
    short* W2cat = (short*)(ws + 32 * MW);               // 3*512*256 shorts
    short* msgWb = W2cat + 3 * 512 * 256;                // 3*256*512 shorts
    short* Bcat  = msgWb + 3 * 256 * 512;                // 3*1024*512 shorts (interleaved)
    short* Asd   = Bcat + 3 * 1024 * 512;                // 3*128*512 shorts
    float* bias4 = (float*)(Asd + 3 * 128 * 512);        // 3*1024 floats
    int* mask    = (int*)(bias4 + 3 * 1024);
    int* logical = mask + B_ * L_;
    int* pol     = logical + B_ * L_;
    int* nvalid  = pol + B_ * L_;

    // weight prep
    prep_w2<<<(3 * 512 * 256 + 255) / 256, 256, 0, stream>>>(gpW, gfW, W2cat);
    f2bf_kernel<<<(3 * 256 * 512 + 255) / 256, 256, 0, stream>>>(msgW, msgWb, 3 * 256 * 512);
    prep_gru_i<<<(3 * 1024 * 512 + 255) / 256, 256, 0, stream>>>(Wih, Whh, Bcat);
    prep_asd<<<(3 * 128 * 512 + 255) / 256, 256, 0, stream>>>(gpas, gpad, gfas, gfad, Asd);
    prep_bias4<<<12, 256, 0, stream>>>(bih, bhh, bias4);

    scan_kernel<<<B_, L_, 0, stream>>>(x, mask, logical, pol, nvalid);
    embed_kernel<<<B_ * L_ / 4, 256, 0, stream>>>(x, emb, pos, hb);

    const int DILS[LAY] = {1, 2, 4};

    for (int l = 0; l < LAY; l++) {
        int dil = DILS[l];
        // hpb2 = hb @ [gpW;gfW]^T   (N=512 -> CB=4, cbBits=2, bf16 out)
        bgemm<<<256 * 4, 256, 0, stream>>>(hb, nullptr, W2cat + (size_t)l * 512 * 256,
                                           hpb2, nullptr, nullptr,
                                           256, 256, 512, 512, 2, GF_OBF16);
        // Ssd = hpb2 @ Asd^T   (CB=1, 16 real cols, fp32, ldc=16)
        bgemm<<<256, 256, 0, stream>>>(hpb2, nullptr, Asd + (size_t)l * 128 * 512,
                                       Ssd, nullptr, nullptr,
                                       512, 512, 16, 16, 0, 0);
        // sparse GAT aggregation, both dirs in one wave, short8-vectorized
        agg_fused<<<8192, 256, 0, stream>>>(hpb2, Ssd, mask, logical, pol, nvalid, mb, dil);
        // mm = relu(m @ msgW^T + msgb) -> bf16  (CB=2, overwrites Ssd region)
        bgemm<<<256 * 2, 256, 0, stream>>>(mb, nullptr, msgWb + (size_t)l * 256 * 512,
                                           mmb, msgb + l * C_, nullptr,
                                           512, 512, 256, 256, 1,
                                           GF_BIAS | GF_RELU | GF_OBF16);
        // GRU GEMM (N=1024 interleaved) + fast-gate epilogue -> hn2b bf16 [32768,256]
        bgemm<<<256 * 8, 256, 0, stream>>>(mmb, hb, Bcat + (size_t)l * 1024 * 512,
                                           hn2b, bias4 + l * 1024, hb,
                                           512, 256, 256, 1024, 3, GF_GRU);
        // LayerNorm + mask -> hb
        ln_kernel<<<8192, 256, 0, stream>>>(hn2b, hb, mask, lng + l * C_, lnb + l * C_);
    }

    pool_head_kernel<<<B_, 1024, 0, stream>>>(hb, mask, pw, pb, h0W, h0b, h1W, h1b, out);
}

// Round 13
// 622.868 us; speedup vs baseline: 1.0662x; 1.0662x over previous
//
#include <hip/hip_runtime.h>
#include <math.h>

#define B_ 64
#define L_ 512
#define C_ 256
#define H_ 4
#define LAY 3
#define NEGV -1e9f

#define GF_BIAS  1
#define GF_RELU  2
#define GF_OBF16 4

typedef __attribute__((ext_vector_type(8))) short short8;
typedef __attribute__((ext_vector_type(4))) short short4v;
typedef __attribute__((ext_vector_type(4))) float floatx4;

static __device__ __forceinline__ float rcp_(float x) { return __builtin_amdgcn_rcpf(x); }
static __device__ __forceinline__ float sig_(float x) { return rcp_(1.f + __expf(-x)); }
static __device__ __forceinline__ float tanh_(float x) {
    float e = __expf(2.f * x);
    return 1.f - 2.f * rcp_(e + 1.f);
}

static __device__ __forceinline__ short f2bf(float f) {
    unsigned x = __float_as_uint(f);
    x += 0x7fffu + ((x >> 16) & 1u);       // round-to-nearest-even to bf16
    return (short)(x >> 16);
}
static __device__ __forceinline__ float bf2f(short s) {
    return __uint_as_float(((unsigned)(unsigned short)s) << 16);
}

// XCD-aligned token swizzle for elementwise consumers (matches GEMM rb%8 = XCD).
static __device__ __forceinline__ int tok_swizzle(int blk) {
    int c8 = blk & 7, i = blk >> 3;
    return (c8 + 8 * (i >> 5)) * 128 + (i & 31) * 4;
}

static __device__ __forceinline__ void gl_lds16(const short* g, short* l) {
    __builtin_amdgcn_global_load_lds(
        (const __attribute__((address_space(1))) unsigned int*)g,
        (__attribute__((address_space(3))) unsigned int*)l, 16, 0, 0);
}

// ---------------- mask / logical-position scan + pos_of_logical ----------------
__global__ void scan_kernel(const int* __restrict__ x, int* __restrict__ mask,
                            int* __restrict__ logical, int* __restrict__ pol,
                            int* __restrict__ nvalid) {
    int b = blockIdx.x, t = threadIdx.x;
    __shared__ int s[L_];
    int m = (x[b * L_ + t] != 0) ? 1 : 0;
    s[t] = m;
    __syncthreads();
    for (int off = 1; off < L_; off <<= 1) {
        int v = (t >= off) ? s[t - off] : 0;
        __syncthreads();
        s[t] += v;
        __syncthreads();
    }
    int cum = s[t];
    int lg = cum - 1; if (lg < 0) lg = 0;
    mask[b * L_ + t] = m;
    logical[b * L_ + t] = lg;
    if (m) pol[b * L_ + lg] = t;
    if (t == L_ - 1) nvalid[b] = cum;
}

// ---------------- hb = bf16((emb[x] + pos*mf)*mf) ----------------
__global__ void embed_kernel(const int* __restrict__ x, const float* __restrict__ emb,
                             const float* __restrict__ pos, short* __restrict__ hb) {
    int t = threadIdx.x;
    int bl = tok_swizzle(blockIdx.x) + (t >> 6);
    int lane = t & 63;
    int xv = x[bl];
    float mf = (xv != 0) ? 1.f : 0.f;
    int l = bl & (L_ - 1);
    float4 e = *(const float4*)&emb[(size_t)xv * C_ + lane * 4];
    float4 p = *(const float4*)&pos[(size_t)l * C_ + lane * 4];
    short4v hv4;
    hv4.x = f2bf((e.x + p.x * mf) * mf);
    hv4.y = f2bf((e.y + p.y * mf) * mf);
    hv4.z = f2bf((e.z + p.z * mf) * mf);
    hv4.w = f2bf((e.w + p.w * mf) * mf);
    *(short4v*)&hb[(size_t)bl * C_ + lane * 4] = hv4;
}

// ---------------- weight prep ----------------
__global__ void f2bf_kernel(const float* __restrict__ s, short* __restrict__ d, int n) {
    int i = blockIdx.x * 256 + threadIdx.x;
    if (i < n) d[i] = f2bf(s[i]);
}

// W2cat[l][512][256]: rows 0..255 = gpW[l], 256..511 = gfW[l]
__global__ void prep_w2(const float* __restrict__ gpW, const float* __restrict__ gfW,
                        short* __restrict__ W2) {
    int i = blockIdx.x * 256 + threadIdx.x;
    if (i >= 3 * 512 * 256) return;
    int k = i & 255, r = (i >> 8) & 511, l = i >> 17;
    float v = (r < 256) ? gpW[((size_t)l * 256 + r) * 256 + k]
                        : gfW[((size_t)l * 256 + (r - 256)) * 256 + k];
    W2[i] = f2bf(v);
}

// AsdW[l][128][256]: row n<16 = (type,dir,head) -> (a_vec @ W_dir) slice, else 0.
// S = hb @ AsdW^T  ==  (hb @ W^T) @ Asd^T  (re-associated; saves K=512 pass)
__global__ void prep_asdw(const float* __restrict__ gpW, const float* __restrict__ gfW,
                          const float* __restrict__ gpas, const float* __restrict__ gpad,
                          const float* __restrict__ gfas, const float* __restrict__ gfad,
                          short* __restrict__ AsdW) {
    int i = blockIdx.x * 256 + threadIdx.x;
    if (i >= 3 * 128 * 256) return;
    int k2 = i & 255, n = (i >> 8) & 127, l = i >> 15;
    float v = 0.f;
    if (n < 16) {
        int type = n >> 3, dir = (n >> 2) & 1, hh = n & 3;
        const float* a = type ? (dir ? gfad : gpad) : (dir ? gfas : gpas);
        const float* W = dir ? gfW : gpW;
        for (int j = 0; j < 64; j++) {
            float av = a[l * 256 + hh * 64 + j];
            float wv = W[((size_t)l * 256 + hh * 64 + j) * 256 + k2];
            v = fmaf(av, wv, v);
        }
    }
    AsdW[i] = f2bf(v);
}

// Interleaved GRU weights: Bc[l][n'][512], n' = 4*ch + g, g in {0:r,1:z,2:i,3:n}.
__global__ void prep_gru_i(const float* __restrict__ Wih, const float* __restrict__ Whh,
                           short* __restrict__ Bc) {
    int i = blockIdx.x * 256 + threadIdx.x;
    if (i >= 3 * 1024 * 512) return;
    int k = i & 511, np = (i >> 9) & 1023, l = i >> 19;
    int ch = np >> 2, g = np & 3;
    float v = 0.f;
    if (g < 2) {
        v = (k < 256) ? Wih[((size_t)l * 768 + g * 256 + ch) * 256 + k]
                      : Whh[((size_t)l * 768 + g * 256 + ch) * 256 + (k - 256)];
    } else if (g == 2) {
        if (k < 256) v = Wih[((size_t)l * 768 + 512 + ch) * 256 + k];
    } else {
        if (k >= 256) v = Whh[((size_t)l * 768 + 512 + ch) * 256 + (k - 256)];
    }
    Bc[i] = f2bf(v);
}

// bias4[l][4*ch+g]
__global__ void prep_bias4(const float* __restrict__ bih, const float* __restrict__ bhh,
                           float* __restrict__ bc) {
    int i = blockIdx.x * 256 + threadIdx.x;
    if (i >= 3 * 1024) return;
    int np = i & 1023, l = i >> 10;
    int ch = np >> 2, g = np & 3;
    float v;
    if (g < 2)       v = bih[l * 768 + g * 256 + ch] + bhh[l * 768 + g * 256 + ch];
    else if (g == 2) v = bih[l * 768 + 512 + ch];
    else             v = bhh[l * 768 + 512 + ch];
    bc[i] = v;
}

// ---------------- plain bf16 MFMA GEMM: C[M,N] = A[M,K] * B[N,K]^T ----------------
// 1D grid, XCD-sequential: id%8 = XCD = rb%8; (id>>3) cycles col-blocks fastest.
// Operand-swapped MFMA: lane owns 4 consecutive cols of one row (packed stores).
__global__ __launch_bounds__(256) void bgemm(const short* __restrict__ A0,
                                             const short* __restrict__ Bw,
                                             void* __restrict__ Cout,
                                             const float* __restrict__ bias,
                                             int K, int lda, int ldc, int nstore,
                                             int cbBits, int flags) {
    __shared__ short As[128 * 32];
    __shared__ short Bs[128 * 32];
    const int id = blockIdx.x;
    const int cb = (id >> 3) & ((1 << cbBits) - 1);
    const int rb = (id & 7) + ((id >> (3 + cbBits)) << 3);
    const int tid = threadIdx.x;
    const int wave = tid >> 6, lane = tid & 63;
    const int wm = wave >> 1, wn = wave & 1;
    const size_t arow0 = (size_t)rb * 128;
    const short* Bb = Bw + (size_t)cb * 128 * K;
    floatx4 acc[4][4];   // [nf][mf]
#pragma unroll
    for (int i = 0; i < 4; i++)
#pragma unroll
        for (int j = 0; j < 4; j++) acc[i][j] = (floatx4)0.f;

    const int srow = lane >> 2;
    const int sq = (lane & 3) * 8;
    const int q = lane >> 4, t16 = lane & 15;

    for (int k0 = 0; k0 < K; k0 += 32) {
        const short* Abase = A0 + arow0 * (size_t)lda + k0;
#pragma unroll
        for (int t = 0; t < 2; ++t) {
            int r = (wave * 2 + t) * 16 + srow;
            gl_lds16(Abase + (size_t)r * lda + sq, &As[r * 32 + sq]);
            gl_lds16(Bb + (size_t)r * K + k0 + sq, &Bs[r * 32 + sq]);
        }
        __syncthreads();
        short8 af[4], bfr[4];
#pragma unroll
        for (int mf = 0; mf < 4; mf++)
            af[mf] = *(const short8*)&As[(wm * 64 + mf * 16 + t16) * 32 + q * 8];
#pragma unroll
        for (int nf = 0; nf < 4; nf++)
            bfr[nf] = *(const short8*)&Bs[(wn * 64 + nf * 16 + t16) * 32 + q * 8];
#pragma unroll
        for (int mf = 0; mf < 4; mf++)
#pragma unroll
            for (int nf = 0; nf < 4; nf++)
                acc[nf][mf] = __builtin_amdgcn_mfma_f32_16x16x32_bf16(
                    bfr[nf], af[mf], acc[nf][mf], 0, 0, 0);
        __syncthreads();
    }

    const int rowbase = rb * 128 + wm * 64;
    const int colbase = cb * 128 + wn * 64;
#pragma unroll
    for (int nf = 0; nf < 4; nf++) {
        int col0 = colbase + nf * 16 + q * 4;
        if (col0 >= nstore) continue;
        float4 bv4 = make_float4(0.f, 0.f, 0.f, 0.f);
        if (flags & GF_BIAS) bv4 = *(const float4*)&bias[col0];
#pragma unroll
        for (int mf = 0; mf < 4; mf++) {
            int row = rowbase + mf * 16 + t16;
            float v0 = acc[nf][mf][0] + bv4.x;
            float v1 = acc[nf][mf][1] + bv4.y;
            float v2 = acc[nf][mf][2] + bv4.z;
            float v3 = acc[nf][mf][3] + bv4.w;
            if (flags & GF_RELU) {
                v0 = fmaxf(v0, 0.f); v1 = fmaxf(v1, 0.f);
                v2 = fmaxf(v2, 0.f); v3 = fmaxf(v3, 0.f);
            }
            size_t base = (size_t)row * ldc + col0;
            if (flags & GF_OBF16) {
                short4v pk;
                pk.x = f2bf(v0); pk.y = f2bf(v1); pk.z = f2bf(v2); pk.w = f2bf(v3);
                *(short4v*)&((short*)Cout)[base] = pk;
            } else {
                float4 pk = make_float4(v0, v1, v2, v3);
                *(float4*)&((float*)Cout)[base] = pk;
            }
        }
    }
}

// ---------------- dedicated GRU GEMM + gate epilogue ----------------
// A = [mmb | hb] K=512, B = Bcat interleaved (N=1024, n'=4ch+g), grid 2048 (cbBits=3).
// Fast transcendentals, hprev register prefetch, LDS-transposed coalesced hn2 store.
__global__ __launch_bounds__(256) void gru_bgemm(const short* __restrict__ mmb,
                                                 const short* __restrict__ hb_in,
                                                 const short* __restrict__ Bw,
                                                 short* __restrict__ hn2b,
                                                 const float* __restrict__ bias4) {
    __shared__ short As[128 * 36];   // K-loop uses stride 32; epilogue staging stride 36
    __shared__ short Bs[128 * 32];
    const int id = blockIdx.x;
    const int cb = (id >> 3) & 7;
    const int rb = (id & 7) + ((id >> 6) << 3);
    const int tid = threadIdx.x;
    const int wave = tid >> 6, lane = tid & 63;
    const int wm = wave >> 1, wn = wave & 1;
    const size_t arow0 = (size_t)rb * 128;
    const short* Bb = Bw + (size_t)cb * 128 * 512;
    const int srow = lane >> 2;
    const int sq = (lane & 3) * 8;
    const int q = lane >> 4, t16 = lane & 15;

    // prefetch h_prev (latency hidden under K-loop)
    float hp[4][4];
#pragma unroll
    for (int nf = 0; nf < 4; nf++) {
        int ch = cb * 32 + wn * 16 + nf * 4 + q;
#pragma unroll
        for (int mf = 0; mf < 4; mf++) {
            int row = rb * 128 + wm * 64 + mf * 16 + t16;
            hp[nf][mf] = bf2f(hb_in[(size_t)row * 256 + ch]);
        }
    }

    floatx4 acc[4][4];
#pragma unroll
    for (int i = 0; i < 4; i++)
#pragma unroll
        for (int j = 0; j < 4; j++) acc[i][j] = (floatx4)0.f;

    for (int k0 = 0; k0 < 512; k0 += 32) {
        const short* Abase = (k0 < 256) ? (mmb + arow0 * 256 + k0)
                                        : (hb_in + arow0 * 256 + (k0 - 256));
#pragma unroll
        for (int t = 0; t < 2; ++t) {
            int r = (wave * 2 + t) * 16 + srow;
            gl_lds16(Abase + (size_t)r * 256 + sq, &As[r * 32 + sq]);
            gl_lds16(Bb + (size_t)r * 512 + k0 + sq, &Bs[r * 32 + sq]);
        }
        __syncthreads();
        short8 af[4], bfr[4];
#pragma unroll
        for (int mf = 0; mf < 4; mf++)
            af[mf] = *(const short8*)&As[(wm * 64 + mf * 16 + t16) * 32 + q * 8];
#pragma unroll
        for (int nf = 0; nf < 4; nf++)
            bfr[nf] = *(const short8*)&Bs[(wn * 64 + nf * 16 + t16) * 32 + q * 8];
#pragma unroll
        for (int mf = 0; mf < 4; mf++)
#pragma unroll
            for (int nf = 0; nf < 4; nf++)
                acc[nf][mf] = __builtin_amdgcn_mfma_f32_16x16x32_bf16(
                    bfr[nf], af[mf], acc[nf][mf], 0, 0, 0);
        __syncthreads();
    }

    const int colbase = cb * 128 + wn * 64;
    // gates -> bf16 hn2 tile in LDS (stride 36: <=2-way bank aliasing, free)
#pragma unroll
    for (int nf = 0; nf < 4; nf++) {
        int col0 = colbase + nf * 16 + q * 4;
        float4 bv4 = *(const float4*)&bias4[col0];
        int chl = wn * 16 + nf * 4 + q;
#pragma unroll
        for (int mf = 0; mf < 4; mf++) {
            int lrow = wm * 64 + mf * 16 + t16;
            float r = sig_(acc[nf][mf][0] + bv4.x);
            float z = sig_(acc[nf][mf][1] + bv4.y);
            float nv = tanh_((acc[nf][mf][2] + bv4.z) + r * (acc[nf][mf][3] + bv4.w));
            As[lrow * 36 + chl] = f2bf((1.f - z) * nv + z * hp[nf][mf]);
        }
    }
    __syncthreads();
    // coalesced write: 128 rows x 32 ch, short4 chunks
    const int chbase = cb * 32;
#pragma unroll
    for (int it = 0; it < 4; it++) {
        int unit = tid + it * 256;
        int rowl = unit >> 3, ck = unit & 7;
        size_t grow = (size_t)rb * 128 + rowl;
        *(short4v*)&hn2b[grow * 256 + chbase + ck * 4] =
            *(const short4v*)&As[rowl * 36 + ck * 4];
    }
}

// ---------------- LayerNorm over hn2 (bf16) + mask -> hb ----------------
__global__ __launch_bounds__(256) void ln_kernel(
    const short* __restrict__ hn2b, short* __restrict__ hb,
    const int* __restrict__ mask,
    const float* __restrict__ lng, const float* __restrict__ lnb) {
    int t = threadIdx.x;
    int bl = tok_swizzle(blockIdx.x) + (t >> 6);
    int lane = t & 63;
    short4v v4 = *(const short4v*)&hn2b[(size_t)bl * C_ + lane * 4];
    float v[4] = {bf2f(v4.x), bf2f(v4.y), bf2f(v4.z), bf2f(v4.w)};
    float s = (v[0] + v[1]) + (v[2] + v[3]);
    float ss = (v[0] * v[0] + v[1] * v[1]) + (v[2] * v[2] + v[3] * v[3]);
#pragma unroll
    for (int off = 32; off; off >>= 1) {
        s += __shfl_xor(s, off);
        ss += __shfl_xor(ss, off);
    }
    float mu = s * (1.f / 256.f);
    float var = ss * (1.f / 256.f) - mu * mu;
    float rstd = rsqrtf(fmaxf(var, 0.f) + 1e-5f);
    float4 lg = *(const float4*)&lng[lane * 4];
    float4 lb = *(const float4*)&lnb[lane * 4];
    float mfv = mask[bl] ? 1.f : 0.f;
    short4v yb;
    yb.x = f2bf(((v[0] - mu) * rstd * lg.x + lb.x) * mfv);
    yb.y = f2bf(((v[1] - mu) * rstd * lg.y + lb.y) * mfv);
    yb.z = f2bf(((v[2] - mu) * rstd * lg.z + lb.z) * mfv);
    yb.w = f2bf(((v[3] - mu) * rstd * lg.w + lb.w) * mfv);
    *(short4v*)&hb[(size_t)bl * C_ + lane * 4] = yb;
}

// ---------------- sparse GAT aggregation, vectorized short8, both dirs ----------------
__global__ __launch_bounds__(256) void agg_fused(
    const short* __restrict__ hpb2, const float* __restrict__ S,
    const int* __restrict__ mask, const int* __restrict__ logical,
    const int* __restrict__ pol, const int* __restrict__ nvalid,
    short* __restrict__ m, int dil) {
    int t = threadIdx.x;
    int bl = tok_swizzle(blockIdx.x) + (t >> 6);
    int sub = t & 63;
    int dir = sub >> 5;
    int slot = sub & 31;
    int cb = slot * 8;
    int head = slot >> 3;
    int b = bl >> 9;

    int mi = mask[bl];
    int li = logical[bl];
    int nv = nvalid[b];
    int js[3]; int nn = 0;
    if (mi) {
#pragma unroll
        for (int k = 1; k <= 3; k++) {
            int lj = dir ? (li - k * dil) : (li + k * dil);
            if (lj >= 0 && lj < nv) js[nn++] = pol[b * L_ + lj];
        }
    }
    int sn = dir * 4 + head, dn = 8 + sn;
    float si = S[(size_t)bl * 16 + sn];
    float di = S[(size_t)bl * 16 + dn];
    float e0 = si + di; e0 = e0 > 0.f ? e0 : 0.2f * e0;
    float emax = e0, ev[3];
    for (int k = 0; k < nn; k++) {
        float djv = S[((size_t)(b * L_ + js[k])) * 16 + dn];
        float e = si + djv; e = e > 0.f ? e : 0.2f * e;
        ev[k] = e; emax = fmaxf(emax, e);
    }
    float w0 = __expf(e0 - emax), den = w0;
    float wv[3];
    for (int k = 0; k < nn; k++) { wv[k] = __expf(ev[k] - emax); den += wv[k]; }
    float rden = rcp_(den);

    size_t base = (size_t)bl * 512 + dir * 256 + cb;
    short8 vself = *(const short8*)&hpb2[base];
    float o[8];
#pragma unroll
    for (int j = 0; j < 8; j++) o[j] = w0 * bf2f(vself[j]);
    for (int k = 0; k < nn; k++) {
        short8 vn = *(const short8*)&hpb2[((size_t)(b * L_ + js[k])) * 512 + dir * 256 + cb];
#pragma unroll
        for (int j = 0; j < 8; j++) o[j] = fmaf(wv[k], bf2f(vn[j]), o[j]);
    }
    short8 ov;
#pragma unroll
    for (int j = 0; j < 8; j++) ov[j] = f2bf(o[j] * rden);
    *(short8*)&m[base] = ov;
}

// ---------------- masked softmax pooling + both heads (bf16 h) ----------------
__global__ __launch_bounds__(1024) void pool_head_kernel(
    const short* __restrict__ hb, const int* __restrict__ mask,
    const float* __restrict__ pw, const float* __restrict__ pb,
    const float* __restrict__ h0W, const float* __restrict__ h0b,
    const float* __restrict__ h1W, const float* __restrict__ h1b,
    float* __restrict__ out) {
    int b = blockIdx.x;
    int t = threadIdx.x;
    int lane = t & 63, wave = t >> 6;
    __shared__ float sc[L_];
    __shared__ float red[20];
    __shared__ float part[4][C_];
    __shared__ float pooled[C_];

    float4 wv = *(const float4*)&pw[lane * 4];
    for (int l = wave; l < L_; l += 16) {
        short4v hv = *(const short4v*)&hb[((size_t)b * L_ + l) * C_ + lane * 4];
        float p = bf2f(hv.x) * wv.x + bf2f(hv.y) * wv.y
                + bf2f(hv.z) * wv.z + bf2f(hv.w) * wv.w;
#pragma unroll
        for (int off = 32; off; off >>= 1) p += __shfl_down(p, off);
        if (lane == 0) sc[l] = mask[b * L_ + l] ? (p + pb[0]) : NEGV;
    }
    __syncthreads();

    float v = (t < L_) ? sc[t] : NEGV;
    float mx = v;
#pragma unroll
    for (int off = 32; off; off >>= 1) mx = fmaxf(mx, __shfl_down(mx, off));
    if (lane == 0) red[wave] = mx;
    __syncthreads();
    if (t == 0) {
        float g = red[0];
        for (int i = 1; i < 16; i++) g = fmaxf(g, red[i]);
        red[16] = g;
    }
    __syncthreads();
    float gmax = red[16];
    float e = (t < L_) ? __expf(v - gmax) : 0.f;
    float ssum = e;
#pragma unroll
    for (int off = 32; off; off >>= 1) ssum += __shfl_down(ssum, off);
    if (lane == 0) red[wave] = ssum;
    __syncthreads();
    if (t == 0) {
        float g = 0.f;
        for (int i = 0; i < 16; i++) g += red[i];
        red[17] = 1.f / g;
    }
    __syncthreads();
    if (t < L_) sc[t] = e * red[17];
    __syncthreads();

    int g = t >> 8, c = t & 255;
    const short* hrow = &hb[((size_t)b * L_ + g * 128) * C_ + c];
    const float* scg = &sc[g * 128];
    float a0 = 0.f, a1 = 0.f, a2 = 0.f, a3 = 0.f;
    for (int l = 0; l < 128; l += 4) {
        a0 = fmaf(scg[l + 0], bf2f(hrow[(size_t)(l + 0) * C_]), a0);
        a1 = fmaf(scg[l + 1], bf2f(hrow[(size_t)(l + 1) * C_]), a1);
        a2 = fmaf(scg[l + 2], bf2f(hrow[(size_t)(l + 2) * C_]), a2);
        a3 = fmaf(scg[l + 3], bf2f(hrow[(size_t)(l + 3) * C_]), a3);
    }
    part[g][c] = (a0 + a1) + (a2 + a3);
    __syncthreads();
    if (t < C_) pooled[t] = (part[0][t] + part[1][t]) + (part[2][t] + part[3][t]);
    __syncthreads();

    for (int o = wave; o < 70; o += 16) {
        const float* W = (o < 50) ? (h0W + (size_t)o * C_) : (h1W + (size_t)(o - 50) * C_);
        float bb = (o < 50) ? h0b[o] : h1b[o - 50];
        float4 w4 = *(const float4*)&W[lane * 4];
        float4 p4 = *(const float4*)&pooled[lane * 4];
        float s = p4.x * w4.x + p4.y * w4.y + p4.z * w4.z + p4.w * w4.w;
#pragma unroll
        for (int off = 32; off; off >>= 1) s += __shfl_down(s, off);
        if (lane == 0) out[b * 70 + o] = s + bb;
    }
}

extern "C" void kernel_launch(void* const* d_in, const int* in_sizes, int n_in,
                              void* d_out, int out_size, void* d_ws, size_t ws_size,
                              hipStream_t stream) {
    const int*   x    = (const int*)d_in[0];
    const float* emb  = (const float*)d_in[1];
    const float* pos  = (const float*)d_in[2];
    const float* gpW  = (const float*)d_in[3];
    const float* gpas = (const float*)d_in[4];
    const float* gpad = (const float*)d_in[5];
    const float* gfW  = (const float*)d_in[6];
    const float* gfas = (const float*)d_in[7];
    const float* gfad = (const float*)d_in[8];
    const float* msgW = (const float*)d_in[9];
    const float* msgb = (const float*)d_in[10];
    const float* Wih  = (const float*)d_in[11];
    const float* bih  = (const float*)d_in[12];
    const float* Whh  = (const float*)d_in[13];
    const float* bhh  = (const float*)d_in[14];
    const float* lng  = (const float*)d_in[15];
    const float* lnb  = (const float*)d_in[16];
    const float* pw   = (const float*)d_in[17];
    const float* pb   = (const float*)d_in[18];
    const float* h0W  = (const float*)d_in[19];
    const float* h0b  = (const float*)d_in[20];
    const float* h1W  = (const float*)d_in[21];
    const float* h1b  = (const float*)d_in[22];
    float* out = (float*)d_out;

    // Workspace layout, units MW = 1Mi floats = 4 MiB:
    //   hn2b bf16 [32768, 256] =  4 MW   -> [ 0,  4)
    //   hb   bf16 [32768, 256] =  4 MW   -> [ 8, 12)
    //   mmb  bf16 [32768, 256] =  4 MW   -> [12, 16)   (also Ssd fp32 [32768,16])
    //   hpb2 bf16 [32768, 512] =  8 MW   -> [16, 24)
    //   mb   bf16 [32768, 512] =  8 MW   -> [24, 32)
    //   weights/bias/masks               -> [32, ~33.3)
    const size_t MW = 1024 * 1024;
    float* ws = (float*)d_ws;
    short* hn2b = (short*)ws;
    short* hb   = (short*)(ws + 8 * MW);
    short* mmb  = (short*)(ws + 12 * MW);
    float* Ssd  = ws + 12 * MW;                          // aliases mmb (timeshared)
    short* hpb2 = (short*)(ws + 16 * MW);
    short* mb   = (short*)(ws + 24 * MW);
    short* W2cat = (short*)(ws + 32 * MW);               // 3*512*256 shorts
    short* msgWb = W2cat + 3 * 512 * 256;                // 3*256*512 shorts
    short* Bcat  = msgWb + 3 * 256 * 512;                // 3*1024*512 shorts (interleaved)
    short* AsdWb = Bcat + 3 * 1024 * 512;                // 3*128*256 shorts
    float* bias4 = (float*)(AsdWb + 3 * 128 * 256);      // 3*1024 floats
    int* mask    = (int*)(bias4 + 3 * 1024);
    int* logical = mask + B_ * L_;
    int* pol     = logical + B_ * L_;
    int* nvalid  = pol + B_ * L_;

    // weight prep
    prep_w2<<<(3 * 512 * 256 + 255) / 256, 256, 0, stream>>>(gpW, gfW, W2cat);
    f2bf_kernel<<<(3 * 256 * 512 + 255) / 256, 256, 0, stream>>>(msgW, msgWb, 3 * 256 * 512);
    prep_gru_i<<<(3 * 1024 * 512 + 255) / 256, 256, 0, stream>>>(Wih, Whh, Bcat);
    prep_asdw<<<(3 * 128 * 256 + 255) / 256, 256, 0, stream>>>(gpW, gfW, gpas, gpad,
                                                               gfas, gfad, AsdWb);
    prep_bias4<<<12, 256, 0, stream>>>(bih, bhh, bias4);

    scan_kernel<<<B_, L_, 0, stream>>>(x, mask, logical, pol, nvalid);
    embed_kernel<<<B_ * L_ / 4, 256, 0, stream>>>(x, emb, pos, hb);

    const int DILS[LAY] = {1, 2, 4};

    for (int l = 0; l < LAY; l++) {
        int dil = DILS[l];
        // Ssd = hb @ AsdW^T  (K=256, 16 real cols, fp32, ldc=16)
        bgemm<<<256, 256, 0, stream>>>(hb, AsdWb + (size_t)l * 128 * 256,
                                       Ssd, nullptr, 256, 256, 16, 16, 0, 0);
        // hpb2 = hb @ [gpW;gfW]^T   (N=512 -> CB=4, cbBits=2, bf16 out)
        bgemm<<<256 * 4, 256, 0, stream>>>(hb, W2cat + (size_t)l * 512 * 256,
                                           hpb2, nullptr, 256, 256, 512, 512, 2, GF_OBF16);
        // sparse GAT aggregation, both dirs in one wave, short8-vectorized
        agg_fused<<<8192, 256, 0, stream>>>(hpb2, Ssd, mask, logical, pol, nvalid, mb, dil);
        // mm = relu(m @ msgW^T + msgb) -> bf16  (CB=2, overwrites Ssd region)
        bgemm<<<256 * 2, 256, 0, stream>>>(mb, msgWb + (size_t)l * 256 * 512,
                                           mmb, msgb + l * C_, 512, 512, 256, 256, 1,
                                           GF_BIAS | GF_RELU | GF_OBF16);
        // dedicated GRU GEMM + fast-gate epilogue -> hn2b bf16 [32768,256]
        gru_bgemm<<<2048, 256, 0, stream>>>(mmb, hb, Bcat + (size_t)l * 1024 * 512,
                                            hn2b, bias4 + l * 1024);
        // LayerNorm + mask -> hb
        ln_kernel<<<8192, 256, 0, stream>>>(hn2b, hb, mask, lng + l * C_, lnb + l * C_);
    }

    pool_head_kernel<<<B_, 1024, 0, stream>>>(hb, mask, pw, pb, h0W, h0b, h1W, h1b, out);
}

// Round 14
// 563.427 us; speedup vs baseline: 1.1787x; 1.1055x over previous
//
#include <hip/hip_runtime.h>
#include <math.h>

#define B_ 64
#define L_ 512
#define C_ 256
#define H_ 4
#define LAY 3
#define NEGV -1e9f

#define GF_BIAS  1
#define GF_RELU  2
#define GF_OBF16 4

typedef __attribute__((ext_vector_type(8))) short short8;
typedef __attribute__((ext_vector_type(4))) short short4v;
typedef __attribute__((ext_vector_type(4))) float floatx4;

static __device__ __forceinline__ float rcp_(float x) { return __builtin_amdgcn_rcpf(x); }
static __device__ __forceinline__ float sig_(float x) { return rcp_(1.f + __expf(-x)); }
static __device__ __forceinline__ float tanh_(float x) {
    float e = __expf(2.f * x);
    return 1.f - 2.f * rcp_(e + 1.f);
}

static __device__ __forceinline__ short f2bf(float f) {
    unsigned x = __float_as_uint(f);
    x += 0x7fffu + ((x >> 16) & 1u);       // round-to-nearest-even to bf16
    return (short)(x >> 16);
}
static __device__ __forceinline__ float bf2f(short s) {
    return __uint_as_float(((unsigned)(unsigned short)s) << 16);
}

// XCD-aligned token swizzle for elementwise consumers (matches GEMM rb%8 = XCD).
static __device__ __forceinline__ int tok_swizzle(int blk) {
    int c8 = blk & 7, i = blk >> 3;
    return (c8 + 8 * (i >> 5)) * 128 + (i & 31) * 4;
}

static __device__ __forceinline__ void gl_lds16(const short* g, short* l) {
    __builtin_amdgcn_global_load_lds(
        (const __attribute__((address_space(1))) unsigned int*)g,
        (__attribute__((address_space(3))) unsigned int*)l, 16, 0, 0);
}

// ---------------- mask / logical-position scan + pos_of_logical ----------------
__global__ void scan_kernel(const int* __restrict__ x, int* __restrict__ mask,
                            int* __restrict__ logical, int* __restrict__ pol,
                            int* __restrict__ nvalid) {
    int b = blockIdx.x, t = threadIdx.x;
    __shared__ int s[L_];
    int m = (x[b * L_ + t] != 0) ? 1 : 0;
    s[t] = m;
    __syncthreads();
    for (int off = 1; off < L_; off <<= 1) {
        int v = (t >= off) ? s[t - off] : 0;
        __syncthreads();
        s[t] += v;
        __syncthreads();
    }
    int cum = s[t];
    int lg = cum - 1; if (lg < 0) lg = 0;
    mask[b * L_ + t] = m;
    logical[b * L_ + t] = lg;
    if (m) pol[b * L_ + lg] = t;
    if (t == L_ - 1) nvalid[b] = cum;
}

// ---------------- hb = bf16((emb[x] + pos*mf)*mf) ----------------
__global__ void embed_kernel(const int* __restrict__ x, const float* __restrict__ emb,
                             const float* __restrict__ pos, short* __restrict__ hb) {
    int t = threadIdx.x;
    int bl = tok_swizzle(blockIdx.x) + (t >> 6);
    int lane = t & 63;
    int xv = x[bl];
    float mf = (xv != 0) ? 1.f : 0.f;
    int l = bl & (L_ - 1);
    float4 e = *(const float4*)&emb[(size_t)xv * C_ + lane * 4];
    float4 p = *(const float4*)&pos[(size_t)l * C_ + lane * 4];
    short4v hv4;
    hv4.x = f2bf((e.x + p.x * mf) * mf);
    hv4.y = f2bf((e.y + p.y * mf) * mf);
    hv4.z = f2bf((e.z + p.z * mf) * mf);
    hv4.w = f2bf((e.w + p.w * mf) * mf);
    *(short4v*)&hb[(size_t)bl * C_ + lane * 4] = hv4;
}

// ---------------- weight prep ----------------
__global__ void f2bf_kernel(const float* __restrict__ s, short* __restrict__ d, int n) {
    int i = blockIdx.x * 256 + threadIdx.x;
    if (i < n) d[i] = f2bf(s[i]);
}

// Wcomb[l][640][256]: rows 0..255 = gpW[l], 256..511 = gfW[l],
// rows 512..527 = AsdW (n = type*8+dir*4+head -> a_vec @ W_dir), rest 0.
__global__ void prep_wcomb(const float* __restrict__ gpW, const float* __restrict__ gfW,
                           const float* __restrict__ gpas, const float* __restrict__ gpad,
                           const float* __restrict__ gfas, const float* __restrict__ gfad,
                           short* __restrict__ Wc) {
    int i = blockIdx.x * 256 + threadIdx.x;
    if (i >= 3 * 640 * 256) return;
    int k = i & 255;
    int r = (i >> 8) % 640;
    int l = i / (640 * 256);
    float v = 0.f;
    if (r < 256) {
        v = gpW[((size_t)l * 256 + r) * 256 + k];
    } else if (r < 512) {
        v = gfW[((size_t)l * 256 + (r - 256)) * 256 + k];
    } else {
        int n = r - 512;
        if (n < 16) {
            int type = n >> 3, dir = (n >> 2) & 1, hh = n & 3;
            const float* a = type ? (dir ? gfad : gpad) : (dir ? gfas : gpas);
            const float* W = dir ? gfW : gpW;
            for (int j = 0; j < 64; j++) {
                float av = a[l * 256 + hh * 64 + j];
                float wv = W[((size_t)l * 256 + hh * 64 + j) * 256 + k];
                v = fmaf(av, wv, v);
            }
        }
    }
    Wc[i] = f2bf(v);
}

// Interleaved GRU weights: Bc[l][n'][512], n' = 4*ch + g, g in {0:r,1:z,2:i,3:n}.
__global__ void prep_gru_i(const float* __restrict__ Wih, const float* __restrict__ Whh,
                           short* __restrict__ Bc) {
    int i = blockIdx.x * 256 + threadIdx.x;
    if (i >= 3 * 1024 * 512) return;
    int k = i & 511, np = (i >> 9) & 1023, l = i >> 19;
    int ch = np >> 2, g = np & 3;
    float v = 0.f;
    if (g < 2) {
        v = (k < 256) ? Wih[((size_t)l * 768 + g * 256 + ch) * 256 + k]
                      : Whh[((size_t)l * 768 + g * 256 + ch) * 256 + (k - 256)];
    } else if (g == 2) {
        if (k < 256) v = Wih[((size_t)l * 768 + 512 + ch) * 256 + k];
    } else {
        if (k >= 256) v = Whh[((size_t)l * 768 + 512 + ch) * 256 + (k - 256)];
    }
    Bc[i] = f2bf(v);
}

// bias4[l][4*ch+g]
__global__ void prep_bias4(const float* __restrict__ bih, const float* __restrict__ bhh,
                           float* __restrict__ bc) {
    int i = blockIdx.x * 256 + threadIdx.x;
    if (i >= 3 * 1024) return;
    int np = i & 1023, l = i >> 10;
    int ch = np >> 2, g = np & 3;
    float v;
    if (g < 2)       v = bih[l * 768 + g * 256 + ch] + bhh[l * 768 + g * 256 + ch];
    else if (g == 2) v = bih[l * 768 + 512 + ch];
    else             v = bhh[l * 768 + 512 + ch];
    bc[i] = v;
}

// ---------------- plain bf16 MFMA GEMM (msg): C[M,N] = A[M,K] * B[N,K]^T ----------------
__global__ __launch_bounds__(256) void bgemm(const short* __restrict__ A0,
                                             const short* __restrict__ Bw,
                                             void* __restrict__ Cout,
                                             const float* __restrict__ bias,
                                             int K, int lda, int ldc, int nstore,
                                             int cbBits, int flags) {
    __shared__ short As[128 * 32];
    __shared__ short Bs[128 * 32];
    const int id = blockIdx.x;
    const int cb = (id >> 3) & ((1 << cbBits) - 1);
    const int rb = (id & 7) + ((id >> (3 + cbBits)) << 3);
    const int tid = threadIdx.x;
    const int wave = tid >> 6, lane = tid & 63;
    const int wm = wave >> 1, wn = wave & 1;
    const size_t arow0 = (size_t)rb * 128;
    const short* Bb = Bw + (size_t)cb * 128 * K;
    floatx4 acc[4][4];   // [nf][mf]
#pragma unroll
    for (int i = 0; i < 4; i++)
#pragma unroll
        for (int j = 0; j < 4; j++) acc[i][j] = (floatx4)0.f;

    const int srow = lane >> 2;
    const int sq = (lane & 3) * 8;
    const int q = lane >> 4, t16 = lane & 15;

    for (int k0 = 0; k0 < K; k0 += 32) {
        const short* Abase = A0 + arow0 * (size_t)lda + k0;
#pragma unroll
        for (int t = 0; t < 2; ++t) {
            int r = (wave * 2 + t) * 16 + srow;
            gl_lds16(Abase + (size_t)r * lda + sq, &As[r * 32 + sq]);
            gl_lds16(Bb + (size_t)r * K + k0 + sq, &Bs[r * 32 + sq]);
        }
        __syncthreads();
        short8 af[4], bfr[4];
#pragma unroll
        for (int mf = 0; mf < 4; mf++)
            af[mf] = *(const short8*)&As[(wm * 64 + mf * 16 + t16) * 32 + q * 8];
#pragma unroll
        for (int nf = 0; nf < 4; nf++)
            bfr[nf] = *(const short8*)&Bs[(wn * 64 + nf * 16 + t16) * 32 + q * 8];
#pragma unroll
        for (int mf = 0; mf < 4; mf++)
#pragma unroll
            for (int nf = 0; nf < 4; nf++)
                acc[nf][mf] = __builtin_amdgcn_mfma_f32_16x16x32_bf16(
                    bfr[nf], af[mf], acc[nf][mf], 0, 0, 0);
        __syncthreads();
    }

    const int rowbase = rb * 128 + wm * 64;
    const int colbase = cb * 128 + wn * 64;
#pragma unroll
    for (int nf = 0; nf < 4; nf++) {
        int col0 = colbase + nf * 16 + q * 4;
        if (col0 >= nstore) continue;
        float4 bv4 = make_float4(0.f, 0.f, 0.f, 0.f);
        if (flags & GF_BIAS) bv4 = *(const float4*)&bias[col0];
#pragma unroll
        for (int mf = 0; mf < 4; mf++) {
            int row = rowbase + mf * 16 + t16;
            float v0 = acc[nf][mf][0] + bv4.x;
            float v1 = acc[nf][mf][1] + bv4.y;
            float v2 = acc[nf][mf][2] + bv4.z;
            float v3 = acc[nf][mf][3] + bv4.w;
            if (flags & GF_RELU) {
                v0 = fmaxf(v0, 0.f); v1 = fmaxf(v1, 0.f);
                v2 = fmaxf(v2, 0.f); v3 = fmaxf(v3, 0.f);
            }
            size_t base = (size_t)row * ldc + col0;
            if (flags & GF_OBF16) {
                short4v pk;
                pk.x = f2bf(v0); pk.y = f2bf(v1); pk.z = f2bf(v2); pk.w = f2bf(v3);
                *(short4v*)&((short*)Cout)[base] = pk;
            } else {
                float4 pk = make_float4(v0, v1, v2, v3);
                *(float4*)&((float*)Cout)[base] = pk;
            }
        }
    }
}

// ---------------- projection + Ssd combined GEMM ----------------
// A = hb [32768,256] (K=256), B = Wcomb [640,256]; cb 0..3 -> hpb2 bf16 (ldc 512),
// cb 4 -> Ssd fp32 (ldc 16, 16 real cols). Grid 1280 = 256 rb x 5 cb, XCD-seq.
__global__ __launch_bounds__(256) void projssd_bgemm(const short* __restrict__ A0,
                                                     const short* __restrict__ Bw,
                                                     short* __restrict__ hpb2,
                                                     float* __restrict__ Ssd) {
    __shared__ short As[128 * 32];
    __shared__ short Bs[128 * 32];
    const int id = blockIdx.x;
    const int grp = id >> 3;
    const int cb = grp % 5;
    const int rb = (id & 7) + (grp / 5) * 8;
    const int tid = threadIdx.x;
    const int wave = tid >> 6, lane = tid & 63;
    const int wm = wave >> 1, wn = wave & 1;
    const size_t arow0 = (size_t)rb * 128;
    const short* Bb = Bw + (size_t)cb * 128 * 256;
    floatx4 acc[4][4];
#pragma unroll
    for (int i = 0; i < 4; i++)
#pragma unroll
        for (int j = 0; j < 4; j++) acc[i][j] = (floatx4)0.f;

    const int srow = lane >> 2;
    const int sq = (lane & 3) * 8;
    const int q = lane >> 4, t16 = lane & 15;

    for (int k0 = 0; k0 < 256; k0 += 32) {
        const short* Abase = A0 + arow0 * 256 + k0;
#pragma unroll
        for (int t = 0; t < 2; ++t) {
            int r = (wave * 2 + t) * 16 + srow;
            gl_lds16(Abase + (size_t)r * 256 + sq, &As[r * 32 + sq]);
            gl_lds16(Bb + (size_t)r * 256 + k0 + sq, &Bs[r * 32 + sq]);
        }
        __syncthreads();
        short8 af[4], bfr[4];
#pragma unroll
        for (int mf = 0; mf < 4; mf++)
            af[mf] = *(const short8*)&As[(wm * 64 + mf * 16 + t16) * 32 + q * 8];
#pragma unroll
        for (int nf = 0; nf < 4; nf++)
            bfr[nf] = *(const short8*)&Bs[(wn * 64 + nf * 16 + t16) * 32 + q * 8];
#pragma unroll
        for (int mf = 0; mf < 4; mf++)
#pragma unroll
            for (int nf = 0; nf < 4; nf++)
                acc[nf][mf] = __builtin_amdgcn_mfma_f32_16x16x32_bf16(
                    bfr[nf], af[mf], acc[nf][mf], 0, 0, 0);
        __syncthreads();
    }

    const int rowbase = rb * 128 + wm * 64;
    if (cb < 4) {
        const int colbase = cb * 128 + wn * 64;
#pragma unroll
        for (int nf = 0; nf < 4; nf++) {
            int col0 = colbase + nf * 16 + q * 4;
#pragma unroll
            for (int mf = 0; mf < 4; mf++) {
                int row = rowbase + mf * 16 + t16;
                short4v pk;
                pk.x = f2bf(acc[nf][mf][0]);
                pk.y = f2bf(acc[nf][mf][1]);
                pk.z = f2bf(acc[nf][mf][2]);
                pk.w = f2bf(acc[nf][mf][3]);
                *(short4v*)&hpb2[(size_t)row * 512 + col0] = pk;
            }
        }
    } else {
        // Ssd: cols 512..639 map to 0..127; only first 16 real (wn=0, nf=0)
        if (wn == 0) {
            int col0 = q * 4;   // nf = 0
            if (col0 < 16) {
#pragma unroll
                for (int mf = 0; mf < 4; mf++) {
                    int row = rowbase + mf * 16 + t16;
                    float4 pk = make_float4(acc[0][mf][0], acc[0][mf][1],
                                            acc[0][mf][2], acc[0][mf][3]);
                    *(float4*)&Ssd[(size_t)row * 16 + col0] = pk;
                }
            }
        }
    }
}

// ---------------- dedicated GRU GEMM + gate epilogue ----------------
// A = [mmb | hb] K=512, B = Bcat interleaved (N=1024, n'=4ch+g), grid 2048.
// hprev loaded in epilogue (L2-hot from A staging) to keep K-loop VGPRs low.
__global__ __launch_bounds__(256) void gru_bgemm(const short* __restrict__ mmb,
                                                 const short* __restrict__ hb_in,
                                                 const short* __restrict__ Bw,
                                                 short* __restrict__ hn2b,
                                                 const float* __restrict__ bias4) {
    __shared__ short As[128 * 36];   // K-loop uses stride 32; epilogue staging stride 36
    __shared__ short Bs[128 * 32];
    const int id = blockIdx.x;
    const int cb = (id >> 3) & 7;
    const int rb = (id & 7) + ((id >> 6) << 3);
    const int tid = threadIdx.x;
    const int wave = tid >> 6, lane = tid & 63;
    const int wm = wave >> 1, wn = wave & 1;
    const size_t arow0 = (size_t)rb * 128;
    const short* Bb = Bw + (size_t)cb * 128 * 512;
    const int srow = lane >> 2;
    const int sq = (lane & 3) * 8;
    const int q = lane >> 4, t16 = lane & 15;

    floatx4 acc[4][4];
#pragma unroll
    for (int i = 0; i < 4; i++)
#pragma unroll
        for (int j = 0; j < 4; j++) acc[i][j] = (floatx4)0.f;

    for (int k0 = 0; k0 < 512; k0 += 32) {
        const short* Abase = (k0 < 256) ? (mmb + arow0 * 256 + k0)
                                        : (hb_in + arow0 * 256 + (k0 - 256));
#pragma unroll
        for (int t = 0; t < 2; ++t) {
            int r = (wave * 2 + t) * 16 + srow;
            gl_lds16(Abase + (size_t)r * 256 + sq, &As[r * 32 + sq]);
            gl_lds16(Bb + (size_t)r * 512 + k0 + sq, &Bs[r * 32 + sq]);
        }
        __syncthreads();
        short8 af[4], bfr[4];
#pragma unroll
        for (int mf = 0; mf < 4; mf++)
            af[mf] = *(const short8*)&As[(wm * 64 + mf * 16 + t16) * 32 + q * 8];
#pragma unroll
        for (int nf = 0; nf < 4; nf++)
            bfr[nf] = *(const short8*)&Bs[(wn * 64 + nf * 16 + t16) * 32 + q * 8];
#pragma unroll
        for (int mf = 0; mf < 4; mf++)
#pragma unroll
            for (int nf = 0; nf < 4; nf++)
                acc[nf][mf] = __builtin_amdgcn_mfma_f32_16x16x32_bf16(
                    bfr[nf], af[mf], acc[nf][mf], 0, 0, 0);
        __syncthreads();
    }

    // epilogue: load h_prev (L2-hot), compute gates, stage hn2 tile in LDS
    float hp[4][4];
#pragma unroll
    for (int nf = 0; nf < 4; nf++) {
        int ch = cb * 32 + wn * 16 + nf * 4 + q;
#pragma unroll
        for (int mf = 0; mf < 4; mf++) {
            int row = rb * 128 + wm * 64 + mf * 16 + t16;
            hp[nf][mf] = bf2f(hb_in[(size_t)row * 256 + ch]);
        }
    }
    const int colbase = cb * 128 + wn * 64;
#pragma unroll
    for (int nf = 0; nf < 4; nf++) {
        int col0 = colbase + nf * 16 + q * 4;
        float4 bv4 = *(const float4*)&bias4[col0];
        int chl = wn * 16 + nf * 4 + q;
#pragma unroll
        for (int mf = 0; mf < 4; mf++) {
            int lrow = wm * 64 + mf * 16 + t16;
            float r = sig_(acc[nf][mf][0] + bv4.x);
            float z = sig_(acc[nf][mf][1] + bv4.y);
            float nv = tanh_((acc[nf][mf][2] + bv4.z) + r * (acc[nf][mf][3] + bv4.w));
            As[lrow * 36 + chl] = f2bf((1.f - z) * nv + z * hp[nf][mf]);
        }
    }
    __syncthreads();
    // coalesced write: 128 rows x 32 ch, short4 chunks
    const int chbase = cb * 32;
#pragma unroll
    for (int it = 0; it < 4; it++) {
        int unit = tid + it * 256;
        int rowl = unit >> 3, ck = unit & 7;
        size_t grow = (size_t)rb * 128 + rowl;
        *(short4v*)&hn2b[grow * 256 + chbase + ck * 4] =
            *(const short4v*)&As[rowl * 36 + ck * 4];
    }
}

// ---------------- LayerNorm over hn2 (bf16) + mask -> hb ----------------
__global__ __launch_bounds__(256) void ln_kernel(
    const short* __restrict__ hn2b, short* __restrict__ hb,
    const int* __restrict__ mask,
    const float* __restrict__ lng, const float* __restrict__ lnb) {
    int t = threadIdx.x;
    int bl = tok_swizzle(blockIdx.x) + (t >> 6);
    int lane = t & 63;
    short4v v4 = *(const short4v*)&hn2b[(size_t)bl * C_ + lane * 4];
    float v[4] = {bf2f(v4.x), bf2f(v4.y), bf2f(v4.z), bf2f(v4.w)};
    float s = (v[0] + v[1]) + (v[2] + v[3]);
    float ss = (v[0] * v[0] + v[1] * v[1]) + (v[2] * v[2] + v[3] * v[3]);
#pragma unroll
    for (int off = 32; off; off >>= 1) {
        s += __shfl_xor(s, off);
        ss += __shfl_xor(ss, off);
    }
    float mu = s * (1.f / 256.f);
    float var = ss * (1.f / 256.f) - mu * mu;
    float rstd = rsqrtf(fmaxf(var, 0.f) + 1e-5f);
    float4 lg = *(const float4*)&lng[lane * 4];
    float4 lb = *(const float4*)&lnb[lane * 4];
    float mfv = mask[bl] ? 1.f : 0.f;
    short4v yb;
    yb.x = f2bf(((v[0] - mu) * rstd * lg.x + lb.x) * mfv);
    yb.y = f2bf(((v[1] - mu) * rstd * lg.y + lb.y) * mfv);
    yb.z = f2bf(((v[2] - mu) * rstd * lg.z + lb.z) * mfv);
    yb.w = f2bf(((v[3] - mu) * rstd * lg.w + lb.w) * mfv);
    *(short4v*)&hb[(size_t)bl * C_ + lane * 4] = yb;
}

// ---------------- sparse GAT aggregation, vectorized short8, both dirs ----------------
__global__ __launch_bounds__(256) void agg_fused(
    const short* __restrict__ hpb2, const float* __restrict__ S,
    const int* __restrict__ mask, const int* __restrict__ logical,
    const int* __restrict__ pol, const int* __restrict__ nvalid,
    short* __restrict__ m, int dil) {
    int t = threadIdx.x;
    int bl = tok_swizzle(blockIdx.x) + (t >> 6);
    int sub = t & 63;
    int dir = sub >> 5;
    int slot = sub & 31;
    int cb = slot * 8;
    int head = slot >> 3;
    int b = bl >> 9;

    int mi = mask[bl];
    int li = logical[bl];
    int nv = nvalid[b];
    int js[3]; int nn = 0;
    if (mi) {
#pragma unroll
        for (int k = 1; k <= 3; k++) {
            int lj = dir ? (li - k * dil) : (li + k * dil);
            if (lj >= 0 && lj < nv) js[nn++] = pol[b * L_ + lj];
        }
    }
    int sn = dir * 4 + head, dn = 8 + sn;
    float si = S[(size_t)bl * 16 + sn];
    float di = S[(size_t)bl * 16 + dn];
    float e0 = si + di; e0 = e0 > 0.f ? e0 : 0.2f * e0;
    float emax = e0, ev[3];
    for (int k = 0; k < nn; k++) {
        float djv = S[((size_t)(b * L_ + js[k])) * 16 + dn];
        float e = si + djv; e = e > 0.f ? e : 0.2f * e;
        ev[k] = e; emax = fmaxf(emax, e);
    }
    float w0 = __expf(e0 - emax), den = w0;
    float wv[3];
    for (int k = 0; k < nn; k++) { wv[k] = __expf(ev[k] - emax); den += wv[k]; }
    float rden = rcp_(den);

    size_t base = (size_t)bl * 512 + dir * 256 + cb;
    short8 vself = *(const short8*)&hpb2[base];
    float o[8];
#pragma unroll
    for (int j = 0; j < 8; j++) o[j] = w0 * bf2f(vself[j]);
    for (int k = 0; k < nn; k++) {
        short8 vn = *(const short8*)&hpb2[((size_t)(b * L_ + js[k])) * 512 + dir * 256 + cb];
#pragma unroll
        for (int j = 0; j < 8; j++) o[j] = fmaf(wv[k], bf2f(vn[j]), o[j]);
    }
    short8 ov;
#pragma unroll
    for (int j = 0; j < 8; j++) ov[j] = f2bf(o[j] * rden);
    *(short8*)&m[base] = ov;
}

// ---------------- masked softmax pooling + both heads (bf16 h) ----------------
__global__ __launch_bounds__(1024) void pool_head_kernel(
    const short* __restrict__ hb, const int* __restrict__ mask,
    const float* __restrict__ pw, const float* __restrict__ pb,
    const float* __restrict__ h0W, const float* __restrict__ h0b,
    const float* __restrict__ h1W, const float* __restrict__ h1b,
    float* __restrict__ out) {
    int b = blockIdx.x;
    int t = threadIdx.x;
    int lane = t & 63, wave = t >> 6;
    __shared__ float sc[L_];
    __shared__ float red[20];
    __shared__ float part[4][C_];
    __shared__ float pooled[C_];

    float4 wv = *(const float4*)&pw[lane * 4];
    for (int l = wave; l < L_; l += 16) {
        short4v hv = *(const short4v*)&hb[((size_t)b * L_ + l) * C_ + lane * 4];
        float p = bf2f(hv.x) * wv.x + bf2f(hv.y) * wv.y
                + bf2f(hv.z) * wv.z + bf2f(hv.w) * wv.w;
#pragma unroll
        for (int off = 32; off; off >>= 1) p += __shfl_down(p, off);
        if (lane == 0) sc[l] = mask[b * L_ + l] ? (p + pb[0]) : NEGV;
    }
    __syncthreads();

    float v = (t < L_) ? sc[t] : NEGV;
    float mx = v;
#pragma unroll
    for (int off = 32; off; off >>= 1) mx = fmaxf(mx, __shfl_down(mx, off));
    if (lane == 0) red[wave] = mx;
    __syncthreads();
    if (t == 0) {
        float g = red[0];
        for (int i = 1; i < 16; i++) g = fmaxf(g, red[i]);
        red[16] = g;
    }
    __syncthreads();
    float gmax = red[16];
    float e = (t < L_) ? __expf(v - gmax) : 0.f;
    float ssum = e;
#pragma unroll
    for (int off = 32; off; off >>= 1) ssum += __shfl_down(ssum, off);
    if (lane == 0) red[wave] = ssum;
    __syncthreads();
    if (t == 0) {
        float g = 0.f;
        for (int i = 0; i < 16; i++) g += red[i];
        red[17] = 1.f / g;
    }
    __syncthreads();
    if (t < L_) sc[t] = e * red[17];
    __syncthreads();

    int g = t >> 8, c = t & 255;
    const short* hrow = &hb[((size_t)b * L_ + g * 128) * C_ + c];
    const float* scg = &sc[g * 128];
    float a0 = 0.f, a1 = 0.f, a2 = 0.f, a3 = 0.f;
    for (int l = 0; l < 128; l += 4) {
        a0 = fmaf(scg[l + 0], bf2f(hrow[(size_t)(l + 0) * C_]), a0);
        a1 = fmaf(scg[l + 1], bf2f(hrow[(size_t)(l + 1) * C_]), a1);
        a2 = fmaf(scg[l + 2], bf2f(hrow[(size_t)(l + 2) * C_]), a2);
        a3 = fmaf(scg[l + 3], bf2f(hrow[(size_t)(l + 3) * C_]), a3);
    }
    part[g][c] = (a0 + a1) + (a2 + a3);
    __syncthreads();
    if (t < C_) pooled[t] = (part[0][t] + part[1][t]) + (part[2][t] + part[3][t]);
    __syncthreads();

    for (int o = wave; o < 70; o += 16) {
        const float* W = (o < 50) ? (h0W + (size_t)o * C_) : (h1W + (size_t)(o - 50) * C_);
        float bb = (o < 50) ? h0b[o] : h1b[o - 50];
        float4 w4 = *(const float4*)&W[lane * 4];
        float4 p4 = *(const float4*)&pooled[lane * 4];
        float s = p4.x * w4.x + p4.y * w4.y + p4.z * w4.z + p4.w * w4.w;
#pragma unroll
        for (int off = 32; off; off >>= 1) s += __shfl_down(s, off);
        if (lane == 0) out[b * 70 + o] = s + bb;
    }
}

extern "C" void kernel_launch(void* const* d_in, const int* in_sizes, int n_in,
                              void* d_out, int out_size, void* d_ws, size_t ws_size,
                              hipStream_t stream) {
    const int*   x    = (const int*)d_in[0];
    const float* emb  = (const float*)d_in[1];
    const float* pos  = (const float*)d_in[2];
    const float* gpW  = (const float*)d_in[3];
    const float* gpas = (const float*)d_in[4];
    const float* gpad = (const float*)d_in[5];
    const float* gfW  = (const float*)d_in[6];
    const float* gfas = (const float*)d_in[7];
    const float* gfad = (const float*)d_in[8];
    const float* msgW = (const float*)d_in[9];
    const float* msgb = (const float*)d_in[10];
    const float* Wih  = (const float*)d_in[11];
    const float* bih  = (const float*)d_in[12];
    const float* Whh  = (const float*)d_in[13];
    const float* bhh  = (const float*)d_in[14];
    const float* lng  = (const float*)d_in[15];
    const float* lnb  = (const float*)d_in[16];
    const float* pw   = (const float*)d_in[17];
    const float* pb   = (const float*)d_in[18];
    const float* h0W  = (const float*)d_in[19];
    const float* h0b  = (const float*)d_in[20];
    const float* h1W  = (const float*)d_in[21];
    const float* h1b  = (const float*)d_in[22];
    float* out = (float*)d_out;

    // Workspace layout, units MW = 1Mi floats = 4 MiB:
    //   hn2b bf16 [32768, 256] =  4 MW   -> [ 0,  4)
    //   hb   bf16 [32768, 256] =  4 MW   -> [ 8, 12)
    //   mmb  bf16 [32768, 256] =  4 MW   -> [12, 16)   (also Ssd fp32 [32768,16])
    //   hpb2 bf16 [32768, 512] =  8 MW   -> [16, 24)
    //   mb   bf16 [32768, 512] =  8 MW   -> [24, 32)
    //   weights/bias/masks               -> [32, ~33.3)
    const size_t MW = 1024 * 1024;
    float* ws = (float*)d_ws;
    short* hn2b = (short*)ws;
    short* hb   = (short*)(ws + 8 * MW);
    short* mmb  = (short*)(ws + 12 * MW);
    float* Ssd  = ws + 12 * MW;                          // aliases mmb (timeshared)
    short* hpb2 = (short*)(ws + 16 * MW);
    short* mb   = (short*)(ws + 24 * MW);
    short* Wcomb = (short*)(ws + 32 * MW);               // 3*640*256 shorts
    short* msgWb = Wcomb + 3 * 640 * 256;                // 3*256*512 shorts
    short* Bcat  = msgWb + 3 * 256 * 512;                // 3*1024*512 shorts (interleaved)
    float* bias4 = (float*)(Bcat + 3 * 1024 * 512);      // 3*1024 floats
    int* mask    = (int*)(bias4 + 3 * 1024);
    int* logical = mask + B_ * L_;
    int* pol     = logical + B_ * L_;
    int* nvalid  = pol + B_ * L_;

    // weight prep
    prep_wcomb<<<(3 * 640 * 256 + 255) / 256, 256, 0, stream>>>(gpW, gfW, gpas, gpad,
                                                                gfas, gfad, Wcomb);
    f2bf_kernel<<<(3 * 256 * 512 + 255) / 256, 256, 0, stream>>>(msgW, msgWb, 3 * 256 * 512);
    prep_gru_i<<<(3 * 1024 * 512 + 255) / 256, 256, 0, stream>>>(Wih, Whh, Bcat);
    prep_bias4<<<12, 256, 0, stream>>>(bih, bhh, bias4);

    scan_kernel<<<B_, L_, 0, stream>>>(x, mask, logical, pol, nvalid);
    embed_kernel<<<B_ * L_ / 4, 256, 0, stream>>>(x, emb, pos, hb);

    const int DILS[LAY] = {1, 2, 4};

    for (int l = 0; l < LAY; l++) {
        int dil = DILS[l];
        // hpb2 (N=512 bf16) + Ssd (16 fp32 cols) in one dispatch
        projssd_bgemm<<<256 * 5, 256, 0, stream>>>(hb, Wcomb + (size_t)l * 640 * 256,
                                                   hpb2, Ssd);
        // sparse GAT aggregation, both dirs in one wave, short8-vectorized
        agg_fused<<<8192, 256, 0, stream>>>(hpb2, Ssd, mask, logical, pol, nvalid, mb, dil);
        // mm = relu(m @ msgW^T + msgb) -> bf16  (CB=2, overwrites Ssd region)
        bgemm<<<256 * 2, 256, 0, stream>>>(mb, msgWb + (size_t)l * 256 * 512,
                                           mmb, msgb + l * C_, 512, 512, 256, 256, 1,
                                           GF_BIAS | GF_RELU | GF_OBF16);
        // dedicated GRU GEMM + fast-gate epilogue -> hn2b bf16 [32768,256]
        gru_bgemm<<<2048, 256, 0, stream>>>(mmb, hb, Bcat + (size_t)l * 1024 * 512,
                                            hn2b, bias4 + l * 1024);
        // LayerNorm + mask -> hb
        ln_kernel<<<8192, 256, 0, stream>>>(hn2b, hb, mask, lng + l * C_, lnb + l * C_);
    }

    pool_head_kernel<<<B_, 1024, 0, stream>>>(hb, mask, pw, pb, h0W, h0b, h1W, h1b, out);
}